// Round 9
// baseline (2020.606 us; speedup 1.0000x reference)
//
#include <hip/hip_runtime.h>
#include <stdint.h>

#define N_NODES 100000
#define N_EDGES 1600000
#define D 128
#define ROWS_PAD 100096            // = NBUCKETS * NPB
#define NPB 128                    // dst nodes per bucket
#define NBUCKETS ((N_NODES + NPB - 1) / NPB)   // 782
#define CAP 4096                   // slots per bucket (mean load 2048, std ~45)
#define AGG_LD 132                 // LDS row stride in f32 (+4 pad: bank-conflict-free MFMA reads)

typedef long long i64;
typedef __attribute__((ext_vector_type(8))) short bf16x8;
typedef __attribute__((ext_vector_type(4))) float f32x4;
typedef __attribute__((ext_vector_type(4))) float fv4;
typedef __attribute__((ext_vector_type(4))) unsigned short usv4;

// f32 -> bf16 round-to-nearest-even (finite inputs)
__device__ __forceinline__ unsigned short f2bf(float f) {
    union { float f; unsigned u; } v; v.f = f;
    unsigned r = v.u + 0x7fff + ((v.u >> 16) & 1);
    return (unsigned short)(r >> 16);
}
__device__ __forceinline__ float bf2f(unsigned short h) {
    union { unsigned u; float f; } v; v.u = ((unsigned)h) << 16;
    return v.f;
}

// ===========================================================================
// Zero per-bucket cursors (every call — graph replays).
// ===========================================================================
__global__ __launch_bounds__(256) void zero_cursor_kernel(int* __restrict__ cursor)
{
    const int i = blockIdx.x * 256 + threadIdx.x;
    if (i < NBUCKETS) cursor[i] = 0;
}

// ===========================================================================
// Phase A: radix-style binning. Edge order (ea sequential, nt).
// msg = bf16(relu(x[src]+ea[e])) appended to bucket(dst)'s stream.
// 782 append-streams write quasi-sequentially (radix-scatter pattern).
// Half-wave per edge, 8 edges per wave.
// ===========================================================================
__global__ __launch_bounds__(256) void bin_kernel(
    const float* __restrict__ x,
    const int*   __restrict__ srcIdx,
    const int*   __restrict__ dstIdx,
    const float* __restrict__ ea,
    int*            __restrict__ cursor,
    unsigned short* __restrict__ payload,
    int*            __restrict__ idxbuf)
{
    const int wave = threadIdx.x >> 6;
    const int lane = threadIdx.x & 63;
    const int half = lane >> 5;
    const int c4   = (lane & 31) * 4;
    const i64 e0 = (i64)blockIdx.x * 32 + wave * 8;

    #pragma unroll
    for (int k = 0; k < 8; k += 2) {
        const i64 e = e0 + k + half;
        const int s = srcIdx[e];
        const int d = dstIdx[e];
        const int bucket = d >> 7;          // NPB = 128
        const int dl     = d & 127;

        int pos = 0;
        if ((lane & 31) == 0) pos = atomicAdd(&cursor[bucket], 1);
        pos = __shfl(pos, half * 32);       // broadcast from half's leader

        if (pos < CAP) {                    // overflow guard (never expected)
            const i64 slot = (i64)bucket * CAP + pos;
            const fv4 xv = *reinterpret_cast<const fv4*>(x + (i64)s * D + c4);
            const fv4 ev = __builtin_nontemporal_load(
                reinterpret_cast<const fv4*>(ea + e * D + c4));
            usv4 m;
            m.x = f2bf(fmaxf(xv.x + ev.x, 0.f));
            m.y = f2bf(fmaxf(xv.y + ev.y, 0.f));
            m.z = f2bf(fmaxf(xv.z + ev.z, 0.f));
            m.w = f2bf(fmaxf(xv.w + ev.w, 0.f));
            __builtin_nontemporal_store(m,
                reinterpret_cast<usv4*>(payload + slot * D + c4));
            if ((lane & 31) == 0) idxbuf[slot] = dl;
        }
    }
}

// ===========================================================================
// Phase B fused with MLP1: one WG per bucket.
//  1) zero LDS agg[128][132] f32
//  2) stream this bucket's payload sequentially, LDS-atomicAdd into agg
//  3) MFMA: h1[row] = bf16(relu((x[row]+agg[row]) @ W1 + b1)) for the
//     bucket's 128 rows (pads: x=0, agg=0 -> relu(b1), discarded downstream).
// MFMA maps (m92-verified): A row=lane&15, k=8*(lane>>4)+j (B same k-map);
// C col=lane&15, row=(lane>>4)*4+reg.
// ===========================================================================
__global__ __launch_bounds__(256) void bucket_mlp1_kernel(
    const float* __restrict__ x,
    const int*   __restrict__ cursor,
    const unsigned short* __restrict__ payload,
    const int*   __restrict__ idxbuf,
    const float* __restrict__ w,              // [D][D] f32, w[k*D+col]
    const float* __restrict__ bias,
    unsigned short* __restrict__ hout)        // [ROWS_PAD][D] bf16
{
    __shared__ float agg[NPB][AGG_LD];        // 67584 B

    const int tid  = threadIdx.x;
    const int wave = tid >> 6;
    const int lane = tid & 63;
    const int g    = lane >> 4;
    const int lr   = lane & 15;
    const int colbase = wave * 32;
    const int bucket  = blockIdx.x;

    // zero LDS
    for (int i = tid; i < NPB * AGG_LD; i += 256)
        (&agg[0][0])[i] = 0.f;

    // B-fragments (w1 -> bf16 regs), independent of LDS
    bf16x8 bfrag[4][2];
    #pragma unroll
    for (int ks = 0; ks < 4; ++ks) {
        #pragma unroll
        for (int nt = 0; nt < 2; ++nt) {
            const int col = colbase + nt * 16 + lr;
            const int k0  = ks * 32 + g * 8;
            bf16x8 f;
            #pragma unroll
            for (int j = 0; j < 8; ++j)
                f[j] = (short)f2bf(w[(k0 + j) * D + col]);
            bfrag[ks][nt] = f;
        }
    }
    const float bc0 = bias[colbase + lr];
    const float bc1 = bias[colbase + 16 + lr];

    __syncthreads();

    // ---- accumulate: wave per entry (lane = 2 cols, 256B/wave), 4-deep unroll
    const int cnt  = min(cursor[bucket], CAP);
    const i64 base = (i64)bucket * CAP;
    const int c2   = lane * 2;

    int i = wave;
    for (; i + 12 < cnt; i += 16) {
        const int i0 = i, i1 = i + 4, i2 = i + 8, i3 = i + 12;
        const int dl0 = idxbuf[base + i0] & 127;
        const int dl1 = idxbuf[base + i1] & 127;
        const int dl2 = idxbuf[base + i2] & 127;
        const int dl3 = idxbuf[base + i3] & 127;
        const ushort2 m0 = *reinterpret_cast<const ushort2*>(payload + (base + i0) * D + c2);
        const ushort2 m1 = *reinterpret_cast<const ushort2*>(payload + (base + i1) * D + c2);
        const ushort2 m2 = *reinterpret_cast<const ushort2*>(payload + (base + i2) * D + c2);
        const ushort2 m3 = *reinterpret_cast<const ushort2*>(payload + (base + i3) * D + c2);
        atomicAdd(&agg[dl0][c2],     bf2f(m0.x));
        atomicAdd(&agg[dl0][c2 + 1], bf2f(m0.y));
        atomicAdd(&agg[dl1][c2],     bf2f(m1.x));
        atomicAdd(&agg[dl1][c2 + 1], bf2f(m1.y));
        atomicAdd(&agg[dl2][c2],     bf2f(m2.x));
        atomicAdd(&agg[dl2][c2 + 1], bf2f(m2.y));
        atomicAdd(&agg[dl3][c2],     bf2f(m3.x));
        atomicAdd(&agg[dl3][c2 + 1], bf2f(m3.y));
    }
    for (; i < cnt; i += 4) {
        const int dl = idxbuf[base + i] & 127;
        const ushort2 mv = *reinterpret_cast<const ushort2*>(payload + (base + i) * D + c2);
        atomicAdd(&agg[dl][c2],     bf2f(mv.x));
        atomicAdd(&agg[dl][c2 + 1], bf2f(mv.y));
    }

    __syncthreads();

    // ---- MFMA MLP1 on (x + agg)
    const int rowbase0 = bucket * NPB;
    #pragma unroll 1
    for (int sub = 0; sub < 8; ++sub) {
        const int arow = sub * 16 + lr;          // local row in bucket
        const int grow = rowbase0 + arow;        // global row

        bf16x8 afrag[4];
        #pragma unroll
        for (int ks = 0; ks < 4; ++ks) {
            const int k0 = ks * 32 + g * 8;
            float v[8];
            if (grow < N_NODES) {
                const float4 u0 = *reinterpret_cast<const float4*>(x + (i64)grow * D + k0);
                const float4 u1 = *reinterpret_cast<const float4*>(x + (i64)grow * D + k0 + 4);
                v[0] = u0.x; v[1] = u0.y; v[2] = u0.z; v[3] = u0.w;
                v[4] = u1.x; v[5] = u1.y; v[6] = u1.z; v[7] = u1.w;
            } else {
                #pragma unroll
                for (int j = 0; j < 8; ++j) v[j] = 0.f;
            }
            bf16x8 f;
            #pragma unroll
            for (int j = 0; j < 8; ++j)
                f[j] = (short)f2bf(v[j] + agg[arow][k0 + j]);
            afrag[ks] = f;
        }

        f32x4 acc0 = { bc0, bc0, bc0, bc0 };
        f32x4 acc1 = { bc1, bc1, bc1, bc1 };
        #pragma unroll
        for (int ks = 0; ks < 4; ++ks) {
            acc0 = __builtin_amdgcn_mfma_f32_16x16x32_bf16(afrag[ks], bfrag[ks][0], acc0, 0, 0, 0);
            acc1 = __builtin_amdgcn_mfma_f32_16x16x32_bf16(afrag[ks], bfrag[ks][1], acc1, 0, 0, 0);
        }

        #pragma unroll
        for (int r = 0; r < 4; ++r) {
            const int orow = rowbase0 + sub * 16 + g * 4 + r;   // < ROWS_PAD always
            hout[(i64)orow * D + colbase + lr]      = f2bf(fmaxf(acc0[r], 0.f));
            hout[(i64)orow * D + colbase + 16 + lr] = f2bf(fmaxf(acc1[r], 0.f));
        }
    }
}

// ===========================================================================
// MLP2 (unchanged, proven): bf16 in -> f32 out (guarded store)
// ===========================================================================
__global__ __launch_bounds__(256) void mlp2_mfma_kernel(
    const unsigned short* __restrict__ hin,   // [ROWS_PAD][D] bf16
    const float* __restrict__ w,
    const float* __restrict__ bias,
    float* __restrict__ hout)                 // [N_NODES][D] f32
{
    const int tid  = threadIdx.x;
    const int wave = tid >> 6;
    const int lane = tid & 63;
    const int g    = lane >> 4;
    const int lr   = lane & 15;
    const int colbase = wave * 32;

    bf16x8 bfrag[4][2];
    #pragma unroll
    for (int ks = 0; ks < 4; ++ks) {
        #pragma unroll
        for (int nt = 0; nt < 2; ++nt) {
            const int col = colbase + nt * 16 + lr;
            const int k0  = ks * 32 + g * 8;
            bf16x8 f;
            #pragma unroll
            for (int j = 0; j < 8; ++j)
                f[j] = (short)f2bf(w[(k0 + j) * D + col]);
            bfrag[ks][nt] = f;
        }
    }
    const float bc0 = bias[colbase + lr];
    const float bc1 = bias[colbase + 16 + lr];

    const int rowbase0 = blockIdx.x * 128;
    #pragma unroll 1
    for (int sub = 0; sub < 8; ++sub) {
        const int rowbase = rowbase0 + sub * 16;
        const int arow = rowbase + lr;

        bf16x8 afrag[4];
        #pragma unroll
        for (int ks = 0; ks < 4; ++ks)
            afrag[ks] = *reinterpret_cast<const bf16x8*>(
                hin + (i64)arow * D + ks * 32 + g * 8);

        f32x4 acc0 = { bc0, bc0, bc0, bc0 };
        f32x4 acc1 = { bc1, bc1, bc1, bc1 };
        #pragma unroll
        for (int ks = 0; ks < 4; ++ks) {
            acc0 = __builtin_amdgcn_mfma_f32_16x16x32_bf16(afrag[ks], bfrag[ks][0], acc0, 0, 0, 0);
            acc1 = __builtin_amdgcn_mfma_f32_16x16x32_bf16(afrag[ks], bfrag[ks][1], acc1, 0, 0, 0);
        }

        #pragma unroll
        for (int r = 0; r < 4; ++r) {
            const int orow = rowbase + g * 4 + r;
            if (orow < N_NODES) {
                hout[(i64)orow * D + colbase + lr]      = acc0[r];
                hout[(i64)orow * D + colbase + 16 + lr] = acc1[r];
            }
        }
    }
}

// ===========================================================================
// Fallback path (R2-proven) — only if ws too small
// ===========================================================================
__global__ __launch_bounds__(256) void init_acc_kernel(
    const float* __restrict__ x, float* __restrict__ acc)
{
    const int i = blockIdx.x * blockDim.x + threadIdx.x;
    const int n = N_NODES * D / 4;
    if (i < n)
        reinterpret_cast<float4*>(acc)[i] = reinterpret_cast<const float4*>(x)[i];
}

__global__ __launch_bounds__(256) void edge_scatter_kernel(
    const float* __restrict__ x,
    const int*  __restrict__ src,
    const int*  __restrict__ dst,
    const float* __restrict__ ea,
    float* __restrict__ acc)
{
    const int lane = threadIdx.x & 31;
    const int grp  = threadIdx.x >> 5;
    const i64 e = (i64)blockIdx.x * 8 + grp;
    if (e >= N_EDGES) return;
    const int s = src[e];
    const int d = dst[e];
    const int j = lane * 4;
    const float4 xv = *reinterpret_cast<const float4*>(x  + (i64)s * D + j);
    const float4 ev = *reinterpret_cast<const float4*>(ea + e * D + j);
    float4 m;
    m.x = fmaxf(xv.x + ev.x, 0.0f);
    m.y = fmaxf(xv.y + ev.y, 0.0f);
    m.z = fmaxf(xv.z + ev.z, 0.0f);
    m.w = fmaxf(xv.w + ev.w, 0.0f);
    float* pp = acc + (i64)d * D + j;
    atomicAdd(pp + 0, m.x);
    atomicAdd(pp + 1, m.y);
    atomicAdd(pp + 2, m.z);
    atomicAdd(pp + 3, m.w);
}

#define MLP_THREADS 512
#define ROWS_PER_CHUNK 16
#define CHUNKS_PER_BLOCK 4
#define ROWS_PER_BLOCK (ROWS_PER_CHUNK * CHUNKS_PER_BLOCK)

template<bool RELU>
__global__ __launch_bounds__(MLP_THREADS) void mlp_layer_kernel(
    const float* __restrict__ hin,
    const float* __restrict__ w,
    const float* __restrict__ b,
    float* __restrict__ hout)
{
    __shared__ float ws_[D * D];
    __shared__ float bs_[D];
    __shared__ float hrow[ROWS_PER_CHUNK][D];

    const int tid = threadIdx.x;
    for (int t = tid; t < D * D / 4; t += MLP_THREADS)
        reinterpret_cast<float4*>(ws_)[t] = reinterpret_cast<const float4*>(w)[t];
    if (tid < D) bs_[tid] = b[tid];

    const int j = tid & (D - 1);
    const int q = tid >> 7;
    const int rowBase = blockIdx.x * ROWS_PER_BLOCK;

    for (int c = 0; c < CHUNKS_PER_BLOCK; ++c) {
        const int chunkRow = rowBase + c * ROWS_PER_CHUNK;
        __syncthreads();
        {
            const int r   = tid >> 5;
            const int col = (tid & 31) * 4;
            const int gi  = chunkRow + r;
            float4 v = make_float4(0.f, 0.f, 0.f, 0.f);
            if (gi < N_NODES)
                v = *reinterpret_cast<const float4*>(hin + (i64)gi * D + col);
            *reinterpret_cast<float4*>(&hrow[r][col]) = v;
        }
        __syncthreads();

        float acc0 = bs_[j], acc1 = bs_[j], acc2 = bs_[j], acc3 = bs_[j];
        const int r0 = q * 4;
        #pragma unroll 4
        for (int k = 0; k < D; ++k) {
            const float wv = ws_[k * D + j];
            acc0 = fmaf(hrow[r0 + 0][k], wv, acc0);
            acc1 = fmaf(hrow[r0 + 1][k], wv, acc1);
            acc2 = fmaf(hrow[r0 + 2][k], wv, acc2);
            acc3 = fmaf(hrow[r0 + 3][k], wv, acc3);
        }
        if (RELU) {
            acc0 = fmaxf(acc0, 0.f); acc1 = fmaxf(acc1, 0.f);
            acc2 = fmaxf(acc2, 0.f); acc3 = fmaxf(acc3, 0.f);
        }
        const int gi = chunkRow + r0;
        if (gi + 0 < N_NODES) hout[(i64)(gi + 0) * D + j] = acc0;
        if (gi + 1 < N_NODES) hout[(i64)(gi + 1) * D + j] = acc1;
        if (gi + 2 < N_NODES) hout[(i64)(gi + 2) * D + j] = acc2;
        if (gi + 3 < N_NODES) hout[(i64)(gi + 3) * D + j] = acc3;
    }
}

// ===========================================================================
extern "C" void kernel_launch(void* const* d_in, const int* in_sizes, int n_in,
                              void* d_out, int out_size, void* d_ws, size_t ws_size,
                              hipStream_t stream)
{
    const float* x  = (const float*)d_in[0];
    const int*   ei = (const int*)  d_in[1];   // [2, E] int32
    const float* ea = (const float*)d_in[2];
    const float* w1 = (const float*)d_in[3];
    const float* b1 = (const float*)d_in[4];
    const float* w2 = (const float*)d_in[5];
    const float* b2 = (const float*)d_in[6];
    float* out = (float*)d_out;

    const int* src = ei;
    const int* dst = ei + N_EDGES;

    // ws layout: cursor[NBUCKETS] | payload bf16[NBUCKETS*CAP*D] | idx[NBUCKETS*CAP] | h1 bf16[ROWS_PAD*D]
    const size_t PAYLOAD_ELEMS = (size_t)NBUCKETS * CAP * D;
    const size_t IDX_ELEMS     = (size_t)NBUCKETS * CAP;
    const size_t H_ELEMS       = (size_t)ROWS_PAD * D;
    const size_t WS_NEEDED = NBUCKETS * 4 + 128 + PAYLOAD_ELEMS * 2 + IDX_ELEMS * 4 + H_ELEMS * 2;

    if (ws_size >= WS_NEEDED) {
        int* cursor = (int*)d_ws;
        uintptr_t p = (uintptr_t)(cursor + NBUCKETS);
        p = (p + 63) & ~(uintptr_t)63;
        unsigned short* payload = (unsigned short*)p;
        int* idxbuf = (int*)(payload + PAYLOAD_ELEMS);
        unsigned short* h1 = (unsigned short*)(idxbuf + IDX_ELEMS);

        zero_cursor_kernel<<<(NBUCKETS + 255) / 256, 256, 0, stream>>>(cursor);
        bin_kernel<<<N_EDGES / 32, 256, 0, stream>>>(x, src, dst, ea, cursor, payload, idxbuf);
        bucket_mlp1_kernel<<<NBUCKETS, 256, 0, stream>>>(x, cursor, payload, idxbuf, w1, b1, h1);
        mlp2_mfma_kernel<<<ROWS_PAD / 128, 256, 0, stream>>>(h1, w2, b2, out);
    } else {
        const int n = N_NODES * D / 4;
        init_acc_kernel<<<(n + 255) / 256, 256, 0, stream>>>(x, out);
        edge_scatter_kernel<<<(N_EDGES + 7) / 8, 256, 0, stream>>>(x, src, dst, ea, out);
        const int blocks = (N_NODES + ROWS_PER_BLOCK - 1) / ROWS_PER_BLOCK;
        mlp_layer_kernel<true ><<<blocks, MLP_THREADS, 0, stream>>>(out, w1, b1, out);
        mlp_layer_kernel<false><<<blocks, MLP_THREADS, 0, stream>>>(out, w2, b2, out);
    }
}

// Round 10
// 486.678 us; speedup vs baseline: 4.1518x; 4.1518x over previous
//
#include <hip/hip_runtime.h>
#include <stdint.h>

#define N_NODES 100000
#define N_EDGES 1600000
#define D 128
#define ROWS_PAD 100096   // 782 * 128

typedef long long i64;
typedef __attribute__((ext_vector_type(8))) short bf16x8;
typedef __attribute__((ext_vector_type(4))) float f32x4;
typedef __attribute__((ext_vector_type(4))) float fv4;
typedef __attribute__((ext_vector_type(4))) unsigned short usv4;
typedef __attribute__((ext_vector_type(8))) unsigned short usv8;

// f32 -> bf16 round-to-nearest-even (finite inputs)
__device__ __forceinline__ unsigned short f2bf(float f) {
    union { float f; unsigned u; } v; v.f = f;
    unsigned r = v.u + 0x7fff + ((v.u >> 16) & 1);
    return (unsigned short)(r >> 16);
}
__device__ __forceinline__ float bf2f(unsigned short h) {
    union { unsigned u; float f; } v; v.u = ((unsigned)h) << 16;
    return v.f;
}

// ===========================================================================
// x -> bf16 pre-convert (sequential, 25.6 MB out; halves gather's x traffic
// and doubles its L2 residency)
// ===========================================================================
__global__ __launch_bounds__(256) void xcvt_kernel(
    const float* __restrict__ x, unsigned short* __restrict__ xb)
{
    const i64 b = ((i64)blockIdx.x * 256 + threadIdx.x) * 8;
    if (b < (i64)N_NODES * D) {
        const fv4 u0 = *reinterpret_cast<const fv4*>(x + b);
        const fv4 u1 = *reinterpret_cast<const fv4*>(x + b + 4);
        usv8 o;
        o.s0 = f2bf(u0.x); o.s1 = f2bf(u0.y); o.s2 = f2bf(u0.z); o.s3 = f2bf(u0.w);
        o.s4 = f2bf(u1.x); o.s5 = f2bf(u1.y); o.s6 = f2bf(u1.z); o.s7 = f2bf(u1.w);
        *reinterpret_cast<usv8*>(xb + b) = o;
    }
}

// ===========================================================================
// CSR build (proven R2..R7)
// ===========================================================================
#define SCAN_CHUNK 1024
#define SCAN_THREADS 256
#define N_CHUNKS ((N_NODES + SCAN_CHUNK - 1) / SCAN_CHUNK)   // 98

__global__ __launch_bounds__(256) void count_zero_kernel(int* __restrict__ counts)
{
    const int i = blockIdx.x * 256 + threadIdx.x;
    if (i < N_NODES) counts[i] = 0;
}

__global__ __launch_bounds__(256) void hist_kernel(
    const int* __restrict__ dst, int* __restrict__ counts)
{
    const int e = blockIdx.x * 256 + threadIdx.x;
    if (e < N_EDGES) atomicAdd(&counts[dst[e]], 1);
}

__global__ __launch_bounds__(SCAN_THREADS) void scan_pass1(
    const int* __restrict__ counts, int* __restrict__ blockSums)
{
    __shared__ int sdata[SCAN_THREADS];
    const int b = blockIdx.x, t = threadIdx.x;
    const int base = b * SCAN_CHUNK + t * 4;
    int s = 0;
    #pragma unroll
    for (int k = 0; k < 4; ++k) {
        const int i = base + k;
        if (i < N_NODES) s += counts[i];
    }
    sdata[t] = s; __syncthreads();
    for (int off = SCAN_THREADS / 2; off > 0; off >>= 1) {
        if (t < off) sdata[t] += sdata[t + off];
        __syncthreads();
    }
    if (t == 0) blockSums[b] = sdata[0];
}

__global__ __launch_bounds__(128) void scan_pass2(
    int* __restrict__ blockSums, int* __restrict__ offsets)
{
    __shared__ int sh[128];
    const int t = threadIdx.x;
    const int v = (t < N_CHUNKS) ? blockSums[t] : 0;
    sh[t] = v; __syncthreads();
    for (int off = 1; off < 128; off <<= 1) {
        const int add = (t >= off) ? sh[t - off] : 0;
        __syncthreads();
        sh[t] += add;
        __syncthreads();
    }
    const int incl = sh[t];
    if (t < N_CHUNKS) blockSums[t] = incl - v;       // exclusive chunk base
    if (t == N_CHUNKS - 1) offsets[N_NODES] = incl;  // total = N_EDGES
}

__global__ __launch_bounds__(SCAN_THREADS) void scan_pass3(
    const int* __restrict__ counts, const int* __restrict__ blockSums,
    int* __restrict__ offsets, int* __restrict__ cursor)
{
    __shared__ int sh[SCAN_THREADS];
    const int b = blockIdx.x, t = threadIdx.x;
    const int base = b * SCAN_CHUNK + t * 4;
    int v[4]; int s = 0;
    #pragma unroll
    for (int k = 0; k < 4; ++k) {
        const int i = base + k;
        v[k] = (i < N_NODES) ? counts[i] : 0;
        s += v[k];
    }
    sh[t] = s; __syncthreads();
    for (int off = 1; off < SCAN_THREADS; off <<= 1) {
        const int add = (t >= off) ? sh[t - off] : 0;
        __syncthreads();
        sh[t] += add;
        __syncthreads();
    }
    int run = blockSums[b] + (sh[t] - s);
    #pragma unroll
    for (int k = 0; k < 4; ++k) {
        const int i = base + k;
        if (i < N_NODES) { offsets[i] = run; cursor[i] = run; }
        run += v[k];
    }
}

__global__ __launch_bounds__(256) void fill_kernel(
    const int* __restrict__ dst, int* __restrict__ cursor, int* __restrict__ bucket)
{
    const int e = blockIdx.x * 256 + threadIdx.x;
    if (e < N_EDGES) {
        const int pos = atomicAdd(&cursor[dst[e]], 1);
        bucket[pos] = e;
    }
}

// ===========================================================================
// Zero pad rows of h0 (bf16) and h1 (bf16) every call.
// ===========================================================================
__global__ __launch_bounds__(256) void pad_zero_kernel(
    unsigned short* __restrict__ h0, unsigned short* __restrict__ h1)
{
    const int i = blockIdx.x * 256 + threadIdx.x;
    const int PADE = (ROWS_PAD - N_NODES) * D;     // 12288
    if (i < PADE) {
        h0[(i64)N_NODES * D + i] = 0;
        h1[(i64)N_NODES * D + i] = 0;
    }
}

// ===========================================================================
// Gather (R7 structure, x side bf16): wave per node, half-wave per edge.
// Bitonic sort keeps accumulation canonical (replay-deterministic).
// x gathered from bf16 copy (halved L3 traffic, 2x L2 residency);
// ea random 512B nt-read (the irreducible permutation side);
// self term x[node] read f32; h0 written bf16.
// ===========================================================================
#define PAIR(p) {                                                               \
    const int idx = 2*(p) + half;                                               \
    const bool v = idx < n;                                                     \
    int e_ = __shfl(key, idx);                                                  \
    int s_ = __shfl(sk, idx);                                                   \
    e_ = v ? e_ : 0; s_ = v ? s_ : 0;                                           \
    const usv4 xv = *reinterpret_cast<const usv4*>(xb + (i64)s_ * D + c4);      \
    const fv4 ev = __builtin_nontemporal_load(                                  \
        reinterpret_cast<const fv4*>(ea + (i64)e_ * D + c4));                   \
    if (v) {                                                                    \
        acc.x += fmaxf(bf2f(xv.x) + ev.x, 0.f);                                 \
        acc.y += fmaxf(bf2f(xv.y) + ev.y, 0.f);                                 \
        acc.z += fmaxf(bf2f(xv.z) + ev.z, 0.f);                                 \
        acc.w += fmaxf(bf2f(xv.w) + ev.w, 0.f);                                 \
    }                                                                           \
}

__global__ __launch_bounds__(256) void gather_kernel(
    const float* __restrict__ x,
    const unsigned short* __restrict__ xb,
    const int*   __restrict__ srcIdx,
    const float* __restrict__ ea,
    const int*   __restrict__ offsets,
    const int*   __restrict__ bucket,
    unsigned short* __restrict__ h0)
{
    const int wave = threadIdx.x >> 6;
    const int lane = threadIdx.x & 63;
    const int node = blockIdx.x * 4 + wave;
    if (node >= N_NODES) return;
    const int half = lane >> 5;            // 0: even slots, 1: odd slots
    const int c4   = (lane & 31) * 4;      // 4 cols per lane

    const int p0 = offsets[node];
    const int p1 = offsets[node + 1];

    fv4 acc;
    if (half == 0) acc = *reinterpret_cast<const fv4*>(x + (i64)node * D + c4);
    else           acc = (fv4){0.f, 0.f, 0.f, 0.f};

    for (int base = p0; base < p1; base += 64) {
        const int n = min(64, p1 - base);

        int key = 0x7fffffff;
        if (lane < n) key = bucket[base + lane];

        // 64-lane bitonic sort, ascending (INT_MAX pads sink to top lanes)
        #pragma unroll
        for (int k = 2; k <= 64; k <<= 1) {
            #pragma unroll
            for (int j = k >> 1; j > 0; j >>= 1) {
                const int other = __shfl_xor(key, j);
                const bool up    = ((lane & k) == 0);
                const bool lower = ((lane & j) == 0);
                key = (lower == up) ? min(key, other) : max(key, other);
            }
        }

        int sk = 0;
        if (lane < n) sk = srcIdx[key];

        const int npair = (n + 1) >> 1;
        int it = 0;
        for (; it + 3 < npair; it += 4) {
            PAIR(it) PAIR(it + 1) PAIR(it + 2) PAIR(it + 3)
        }
        for (; it < npair; ++it) { PAIR(it) }
    }

    // combine halves: commutative add -> identical in both lanes, deterministic
    acc.x += __shfl_xor(acc.x, 32);
    acc.y += __shfl_xor(acc.y, 32);
    acc.z += __shfl_xor(acc.z, 32);
    acc.w += __shfl_xor(acc.w, 32);

    if (half == 0) {
        usv4 o;
        o.x = f2bf(acc.x); o.y = f2bf(acc.y);
        o.z = f2bf(acc.z); o.w = f2bf(acc.w);
        *reinterpret_cast<usv4*>(h0 + (i64)node * D + c4) = o;
    }
}

// ===========================================================================
// MFMA MLP layers, A-input bf16 (m92-verified 16x16x32 maps:
//   A: row=lane&15, k=8*(lane>>4)+j ; B: col=lane&15, same k-map
//   C: col=lane&15, row=(lane>>4)*4+reg)
// mlp1: bf16 in -> relu -> bf16 out (all ROWS_PAD rows; pads zeroed upstream)
// mlp2: bf16 in -> f32 out (guarded store)
// ===========================================================================
__global__ __launch_bounds__(256) void mlp1_mfma_kernel(
    const unsigned short* __restrict__ hin,   // [ROWS_PAD][D] bf16
    const float* __restrict__ w,              // [D][D] f32, w[k*D+col]
    const float* __restrict__ bias,
    unsigned short* __restrict__ hout)        // [ROWS_PAD][D] bf16
{
    const int tid  = threadIdx.x;
    const int wave = tid >> 6;
    const int lane = tid & 63;
    const int g    = lane >> 4;
    const int lr   = lane & 15;
    const int colbase = wave * 32;

    bf16x8 bfrag[4][2];
    #pragma unroll
    for (int ks = 0; ks < 4; ++ks) {
        #pragma unroll
        for (int nt = 0; nt < 2; ++nt) {
            const int col = colbase + nt * 16 + lr;
            const int k0  = ks * 32 + g * 8;
            bf16x8 f;
            #pragma unroll
            for (int j = 0; j < 8; ++j)
                f[j] = (short)f2bf(w[(k0 + j) * D + col]);
            bfrag[ks][nt] = f;
        }
    }
    const float bc0 = bias[colbase + lr];
    const float bc1 = bias[colbase + 16 + lr];

    const int rowbase0 = blockIdx.x * 128;
    #pragma unroll 1
    for (int sub = 0; sub < 8; ++sub) {
        const int rowbase = rowbase0 + sub * 16;
        const int arow = rowbase + lr;

        bf16x8 afrag[4];
        #pragma unroll
        for (int ks = 0; ks < 4; ++ks)
            afrag[ks] = *reinterpret_cast<const bf16x8*>(
                hin + (i64)arow * D + ks * 32 + g * 8);

        f32x4 acc0 = { bc0, bc0, bc0, bc0 };
        f32x4 acc1 = { bc1, bc1, bc1, bc1 };
        #pragma unroll
        for (int ks = 0; ks < 4; ++ks) {
            acc0 = __builtin_amdgcn_mfma_f32_16x16x32_bf16(afrag[ks], bfrag[ks][0], acc0, 0, 0, 0);
            acc1 = __builtin_amdgcn_mfma_f32_16x16x32_bf16(afrag[ks], bfrag[ks][1], acc1, 0, 0, 0);
        }

        #pragma unroll
        for (int r = 0; r < 4; ++r) {
            const int orow = rowbase + g * 4 + r;
            hout[(i64)orow * D + colbase + lr]      = f2bf(fmaxf(acc0[r], 0.f));
            hout[(i64)orow * D + colbase + 16 + lr] = f2bf(fmaxf(acc1[r], 0.f));
        }
    }
}

__global__ __launch_bounds__(256) void mlp2_mfma_kernel(
    const unsigned short* __restrict__ hin,   // [ROWS_PAD][D] bf16
    const float* __restrict__ w,
    const float* __restrict__ bias,
    float* __restrict__ hout)                 // [N_NODES][D] f32
{
    const int tid  = threadIdx.x;
    const int wave = tid >> 6;
    const int lane = tid & 63;
    const int g    = lane >> 4;
    const int lr   = lane & 15;
    const int colbase = wave * 32;

    bf16x8 bfrag[4][2];
    #pragma unroll
    for (int ks = 0; ks < 4; ++ks) {
        #pragma unroll
        for (int nt = 0; nt < 2; ++nt) {
            const int col = colbase + nt * 16 + lr;
            const int k0  = ks * 32 + g * 8;
            bf16x8 f;
            #pragma unroll
            for (int j = 0; j < 8; ++j)
                f[j] = (short)f2bf(w[(k0 + j) * D + col]);
            bfrag[ks][nt] = f;
        }
    }
    const float bc0 = bias[colbase + lr];
    const float bc1 = bias[colbase + 16 + lr];

    const int rowbase0 = blockIdx.x * 128;
    #pragma unroll 1
    for (int sub = 0; sub < 8; ++sub) {
        const int rowbase = rowbase0 + sub * 16;
        const int arow = rowbase + lr;

        bf16x8 afrag[4];
        #pragma unroll
        for (int ks = 0; ks < 4; ++ks)
            afrag[ks] = *reinterpret_cast<const bf16x8*>(
                hin + (i64)arow * D + ks * 32 + g * 8);

        f32x4 acc0 = { bc0, bc0, bc0, bc0 };
        f32x4 acc1 = { bc1, bc1, bc1, bc1 };
        #pragma unroll
        for (int ks = 0; ks < 4; ++ks) {
            acc0 = __builtin_amdgcn_mfma_f32_16x16x32_bf16(afrag[ks], bfrag[ks][0], acc0, 0, 0, 0);
            acc1 = __builtin_amdgcn_mfma_f32_16x16x32_bf16(afrag[ks], bfrag[ks][1], acc1, 0, 0, 0);
        }

        #pragma unroll
        for (int r = 0; r < 4; ++r) {
            const int orow = rowbase + g * 4 + r;
            if (orow < N_NODES) {
                hout[(i64)orow * D + colbase + lr]      = acc0[r];
                hout[(i64)orow * D + colbase + 16 + lr] = acc1[r];
            }
        }
    }
}

// ===========================================================================
// Fallback path (R2-proven) — only if ws too small
// ===========================================================================
__global__ __launch_bounds__(256) void init_acc_kernel(
    const float* __restrict__ x, float* __restrict__ acc)
{
    const int i = blockIdx.x * blockDim.x + threadIdx.x;
    const int n = N_NODES * D / 4;
    if (i < n)
        reinterpret_cast<float4*>(acc)[i] = reinterpret_cast<const float4*>(x)[i];
}

__global__ __launch_bounds__(256) void edge_scatter_kernel(
    const float* __restrict__ x,
    const int*  __restrict__ src,
    const int*  __restrict__ dst,
    const float* __restrict__ ea,
    float* __restrict__ acc)
{
    const int lane = threadIdx.x & 31;
    const int grp  = threadIdx.x >> 5;
    const i64 e = (i64)blockIdx.x * 8 + grp;
    if (e >= N_EDGES) return;
    const int s = src[e];
    const int d = dst[e];
    const int j = lane * 4;
    const float4 xv = *reinterpret_cast<const float4*>(x  + (i64)s * D + j);
    const float4 ev = *reinterpret_cast<const float4*>(ea + e * D + j);
    float4 m;
    m.x = fmaxf(xv.x + ev.x, 0.0f);
    m.y = fmaxf(xv.y + ev.y, 0.0f);
    m.z = fmaxf(xv.z + ev.z, 0.0f);
    m.w = fmaxf(xv.w + ev.w, 0.0f);
    float* pp = acc + (i64)d * D + j;
    atomicAdd(pp + 0, m.x);
    atomicAdd(pp + 1, m.y);
    atomicAdd(pp + 2, m.z);
    atomicAdd(pp + 3, m.w);
}

#define MLP_THREADS 512
#define ROWS_PER_CHUNK 16
#define CHUNKS_PER_BLOCK 4
#define ROWS_PER_BLOCK (ROWS_PER_CHUNK * CHUNKS_PER_BLOCK)

template<bool RELU>
__global__ __launch_bounds__(MLP_THREADS) void mlp_layer_kernel(
    const float* __restrict__ hin,
    const float* __restrict__ w,
    const float* __restrict__ b,
    float* __restrict__ hout)
{
    __shared__ float ws_[D * D];
    __shared__ float bs_[D];
    __shared__ float hrow[ROWS_PER_CHUNK][D];

    const int tid = threadIdx.x;
    for (int t = tid; t < D * D / 4; t += MLP_THREADS)
        reinterpret_cast<float4*>(ws_)[t] = reinterpret_cast<const float4*>(w)[t];
    if (tid < D) bs_[tid] = b[tid];

    const int j = tid & (D - 1);
    const int q = tid >> 7;
    const int rowBase = blockIdx.x * ROWS_PER_BLOCK;

    for (int c = 0; c < CHUNKS_PER_BLOCK; ++c) {
        const int chunkRow = rowBase + c * ROWS_PER_CHUNK;
        __syncthreads();
        {
            const int r   = tid >> 5;
            const int col = (tid & 31) * 4;
            const int gi  = chunkRow + r;
            float4 v = make_float4(0.f, 0.f, 0.f, 0.f);
            if (gi < N_NODES)
                v = *reinterpret_cast<const float4*>(hin + (i64)gi * D + col);
            *reinterpret_cast<float4*>(&hrow[r][col]) = v;
        }
        __syncthreads();

        float acc0 = bs_[j], acc1 = bs_[j], acc2 = bs_[j], acc3 = bs_[j];
        const int r0 = q * 4;
        #pragma unroll 4
        for (int k = 0; k < D; ++k) {
            const float wv = ws_[k * D + j];
            acc0 = fmaf(hrow[r0 + 0][k], wv, acc0);
            acc1 = fmaf(hrow[r0 + 1][k], wv, acc1);
            acc2 = fmaf(hrow[r0 + 2][k], wv, acc2);
            acc3 = fmaf(hrow[r0 + 3][k], wv, acc3);
        }
        if (RELU) {
            acc0 = fmaxf(acc0, 0.f); acc1 = fmaxf(acc1, 0.f);
            acc2 = fmaxf(acc2, 0.f); acc3 = fmaxf(acc3, 0.f);
        }
        const int gi = chunkRow + r0;
        if (gi + 0 < N_NODES) hout[(i64)(gi + 0) * D + j] = acc0;
        if (gi + 1 < N_NODES) hout[(i64)(gi + 1) * D + j] = acc1;
        if (gi + 2 < N_NODES) hout[(i64)(gi + 2) * D + j] = acc2;
        if (gi + 3 < N_NODES) hout[(i64)(gi + 3) * D + j] = acc3;
    }
}

// ===========================================================================
extern "C" void kernel_launch(void* const* d_in, const int* in_sizes, int n_in,
                              void* d_out, int out_size, void* d_ws, size_t ws_size,
                              hipStream_t stream)
{
    const float* x  = (const float*)d_in[0];
    const int*   ei = (const int*)  d_in[1];   // [2, E] int32
    const float* ea = (const float*)d_in[2];
    const float* w1 = (const float*)d_in[3];
    const float* b1 = (const float*)d_in[4];
    const float* w2 = (const float*)d_in[5];
    const float* b2 = (const float*)d_in[6];
    float* out = (float*)d_out;

    const int* src = ei;
    const int* dst = ei + N_EDGES;

    // ws layout: ints (counts|offsets|cursor|blockSums|bucket) | xb bf16 | h0 bf16 | h1 bf16
    const size_t INT_REGION = (size_t)N_NODES + (N_NODES + 1) + N_NODES + 128 + N_EDGES;
    const size_t X_ELEMS    = (size_t)N_NODES * D;
    const size_t H_ELEMS    = (size_t)ROWS_PAD * D;
    const size_t WS_NEEDED  = INT_REGION * 4 + 64 + (X_ELEMS + 2 * H_ELEMS) * 2;

    if (ws_size >= WS_NEEDED) {
        int* counts    = (int*)d_ws;
        int* offsets   = counts + N_NODES;
        int* cursor    = offsets + (N_NODES + 1);
        int* blockSums = cursor + N_NODES;
        int* bucket    = blockSums + 128;
        uintptr_t p = (uintptr_t)(bucket + N_EDGES);
        p = (p + 63) & ~(uintptr_t)63;
        unsigned short* xb = (unsigned short*)p;
        unsigned short* h0 = xb + X_ELEMS;
        unsigned short* h1 = h0 + H_ELEMS;

        xcvt_kernel<<<(int)(X_ELEMS / 8 + 255) / 256, 256, 0, stream>>>(x, xb);
        count_zero_kernel<<<(N_NODES + 255) / 256, 256, 0, stream>>>(counts);
        hist_kernel<<<(N_EDGES + 255) / 256, 256, 0, stream>>>(dst, counts);
        scan_pass1<<<N_CHUNKS, SCAN_THREADS, 0, stream>>>(counts, blockSums);
        scan_pass2<<<1, 128, 0, stream>>>(blockSums, offsets);
        scan_pass3<<<N_CHUNKS, SCAN_THREADS, 0, stream>>>(counts, blockSums, offsets, cursor);
        fill_kernel<<<(N_EDGES + 255) / 256, 256, 0, stream>>>(dst, cursor, bucket);
        pad_zero_kernel<<<48, 256, 0, stream>>>(h0, h1);
        gather_kernel<<<(N_NODES + 3) / 4, 256, 0, stream>>>(x, xb, src, ea, offsets, bucket, h0);

        const int mlpBlocks = ROWS_PAD / 128;   // 782
        mlp1_mfma_kernel<<<mlpBlocks, 256, 0, stream>>>(h0, w1, b1, h1);
        mlp2_mfma_kernel<<<mlpBlocks, 256, 0, stream>>>(h1, w2, b2, out);
    } else {
        const int n = N_NODES * D / 4;
        init_acc_kernel<<<(n + 255) / 256, 256, 0, stream>>>(x, out);
        edge_scatter_kernel<<<(N_EDGES + 7) / 8, 256, 0, stream>>>(x, src, dst, ea, out);
        const int blocks = (N_NODES + ROWS_PER_BLOCK - 1) / ROWS_PER_BLOCK;
        mlp_layer_kernel<true ><<<blocks, MLP_THREADS, 0, stream>>>(out, w1, b1, out);
        mlp_layer_kernel<false><<<blocks, MLP_THREADS, 0, stream>>>(out, w2, b2, out);
    }
}

// Round 11
// 437.504 us; speedup vs baseline: 4.6185x; 1.1124x over previous
//
#include <hip/hip_runtime.h>
#include <stdint.h>

#define N_NODES 100000
#define N_EDGES 1600000
#define D 128
#define ROWS_PAD 100096   // 782 * 128

typedef long long i64;
typedef __attribute__((ext_vector_type(8))) short bf16x8;
typedef __attribute__((ext_vector_type(4))) float f32x4;
typedef __attribute__((ext_vector_type(4))) float fv4;
typedef __attribute__((ext_vector_type(4))) unsigned short usv4;
typedef __attribute__((ext_vector_type(8))) unsigned short usv8;

// f32 -> bf16 round-to-nearest-even (finite inputs)
__device__ __forceinline__ unsigned short f2bf(float f) {
    union { float f; unsigned u; } v; v.f = f;
    unsigned r = v.u + 0x7fff + ((v.u >> 16) & 1);
    return (unsigned short)(r >> 16);
}
__device__ __forceinline__ float bf2f(unsigned short h) {
    union { unsigned u; float f; } v; v.u = ((unsigned)h) << 16;
    return v.f;
}

// ===========================================================================
// prep: x->bf16 convert (sequential) + zero counts + zero h0 pad rows.
// ===========================================================================
__global__ __launch_bounds__(256) void prep_kernel(
    const float* __restrict__ x, unsigned short* __restrict__ xb,
    int* __restrict__ counts, unsigned short* __restrict__ h0)
{
    const int i = blockIdx.x * 256 + threadIdx.x;      // < 1.6M
    const i64 b = (i64)i * 8;
    if (b < (i64)N_NODES * D) {
        const fv4 u0 = *reinterpret_cast<const fv4*>(x + b);
        const fv4 u1 = *reinterpret_cast<const fv4*>(x + b + 4);
        usv8 o;
        o.s0 = f2bf(u0.x); o.s1 = f2bf(u0.y); o.s2 = f2bf(u0.z); o.s3 = f2bf(u0.w);
        o.s4 = f2bf(u1.x); o.s5 = f2bf(u1.y); o.s6 = f2bf(u1.z); o.s7 = f2bf(u1.w);
        *reinterpret_cast<usv8*>(xb + b) = o;
    }
    if (i < N_NODES) counts[i] = 0;
    if (i < (ROWS_PAD - N_NODES) * D)                   // 12288
        h0[(i64)N_NODES * D + i] = 0;
}

// ===========================================================================
// CSR build (proven R2..R10); fill packs (e, src[e]) into int2 buckets.
// ===========================================================================
#define SCAN_CHUNK 1024
#define SCAN_THREADS 256
#define N_CHUNKS ((N_NODES + SCAN_CHUNK - 1) / SCAN_CHUNK)   // 98

__global__ __launch_bounds__(256) void hist_kernel(
    const int* __restrict__ dst, int* __restrict__ counts)
{
    const int e = blockIdx.x * 256 + threadIdx.x;
    if (e < N_EDGES) atomicAdd(&counts[dst[e]], 1);
}

__global__ __launch_bounds__(SCAN_THREADS) void scan_pass1(
    const int* __restrict__ counts, int* __restrict__ blockSums)
{
    __shared__ int sdata[SCAN_THREADS];
    const int b = blockIdx.x, t = threadIdx.x;
    const int base = b * SCAN_CHUNK + t * 4;
    int s = 0;
    #pragma unroll
    for (int k = 0; k < 4; ++k) {
        const int i = base + k;
        if (i < N_NODES) s += counts[i];
    }
    sdata[t] = s; __syncthreads();
    for (int off = SCAN_THREADS / 2; off > 0; off >>= 1) {
        if (t < off) sdata[t] += sdata[t + off];
        __syncthreads();
    }
    if (t == 0) blockSums[b] = sdata[0];
}

__global__ __launch_bounds__(128) void scan_pass2(
    int* __restrict__ blockSums, int* __restrict__ offsets)
{
    __shared__ int sh[128];
    const int t = threadIdx.x;
    const int v = (t < N_CHUNKS) ? blockSums[t] : 0;
    sh[t] = v; __syncthreads();
    for (int off = 1; off < 128; off <<= 1) {
        const int add = (t >= off) ? sh[t - off] : 0;
        __syncthreads();
        sh[t] += add;
        __syncthreads();
    }
    const int incl = sh[t];
    if (t < N_CHUNKS) blockSums[t] = incl - v;       // exclusive chunk base
    if (t == N_CHUNKS - 1) offsets[N_NODES] = incl;  // total = N_EDGES
}

__global__ __launch_bounds__(SCAN_THREADS) void scan_pass3(
    const int* __restrict__ counts, const int* __restrict__ blockSums,
    int* __restrict__ offsets, int* __restrict__ cursor)
{
    __shared__ int sh[SCAN_THREADS];
    const int b = blockIdx.x, t = threadIdx.x;
    const int base = b * SCAN_CHUNK + t * 4;
    int v[4]; int s = 0;
    #pragma unroll
    for (int k = 0; k < 4; ++k) {
        const int i = base + k;
        v[k] = (i < N_NODES) ? counts[i] : 0;
        s += v[k];
    }
    sh[t] = s; __syncthreads();
    for (int off = 1; off < SCAN_THREADS; off <<= 1) {
        const int add = (t >= off) ? sh[t - off] : 0;
        __syncthreads();
        sh[t] += add;
        __syncthreads();
    }
    int run = blockSums[b] + (sh[t] - s);
    #pragma unroll
    for (int k = 0; k < 4; ++k) {
        const int i = base + k;
        if (i < N_NODES) { offsets[i] = run; cursor[i] = run; }
        run += v[k];
    }
}

__global__ __launch_bounds__(256) void fill2_kernel(
    const int* __restrict__ src, const int* __restrict__ dst,
    int* __restrict__ cursor, int2* __restrict__ bucket2)
{
    const int e = blockIdx.x * 256 + threadIdx.x;
    if (e < N_EDGES) {
        const int pos = atomicAdd(&cursor[dst[e]], 1);
        bucket2[pos] = make_int2(e, src[e]);
    }
}

// ===========================================================================
// Gather (R10 core): wave per node, half-wave per edge. Bitonic sort on edge
// id CARRYING src payload (canonical order -> replay-deterministic, and no
// random srcIdx gather). x side bf16 (L2/L3-resident), ea random 512B nt.
// ===========================================================================
#define PAIR(p) {                                                               \
    const int idx = 2*(p) + half;                                               \
    const bool v = idx < n;                                                     \
    int e_ = __shfl(key, idx);                                                  \
    int s_ = __shfl(sv, idx);                                                   \
    e_ = v ? e_ : 0; s_ = v ? s_ : 0;                                           \
    const usv4 xv = *reinterpret_cast<const usv4*>(xb + (i64)s_ * D + c4);      \
    const fv4 ev = __builtin_nontemporal_load(                                  \
        reinterpret_cast<const fv4*>(ea + (i64)e_ * D + c4));                   \
    if (v) {                                                                    \
        acc.x += fmaxf(bf2f(xv.x) + ev.x, 0.f);                                 \
        acc.y += fmaxf(bf2f(xv.y) + ev.y, 0.f);                                 \
        acc.z += fmaxf(bf2f(xv.z) + ev.z, 0.f);                                 \
        acc.w += fmaxf(bf2f(xv.w) + ev.w, 0.f);                                 \
    }                                                                           \
}

__global__ __launch_bounds__(256) void gather_kernel(
    const unsigned short* __restrict__ xb,
    const float* __restrict__ ea,
    const int*  __restrict__ offsets,
    const int2* __restrict__ bucket2,
    unsigned short* __restrict__ h0)
{
    const int wave = threadIdx.x >> 6;
    const int lane = threadIdx.x & 63;
    const int node = blockIdx.x * 4 + wave;
    if (node >= N_NODES) return;
    const int half = lane >> 5;            // 0: even slots, 1: odd slots
    const int c4   = (lane & 31) * 4;      // 4 cols per lane

    const int p0 = offsets[node];
    const int p1 = offsets[node + 1];

    fv4 acc = (fv4){0.f, 0.f, 0.f, 0.f};
    if (half == 0) {
        const usv4 xv = *reinterpret_cast<const usv4*>(xb + (i64)node * D + c4);
        acc.x = bf2f(xv.x); acc.y = bf2f(xv.y);
        acc.z = bf2f(xv.z); acc.w = bf2f(xv.w);
    }

    for (int base = p0; base < p1; base += 64) {
        const int n = min(64, p1 - base);

        int key = 0x7fffffff, sv = 0;
        if (lane < n) {
            const int2 t = bucket2[base + lane];
            key = t.x; sv = t.y;
        }

        // 64-lane bitonic sort on key, carrying sv (INT_MAX pads sink to top)
        #pragma unroll
        for (int k = 2; k <= 64; k <<= 1) {
            #pragma unroll
            for (int j = k >> 1; j > 0; j >>= 1) {
                const int ok = __shfl_xor(key, j);
                const int os = __shfl_xor(sv, j);
                const bool up    = ((lane & k) == 0);
                const bool lower = ((lane & j) == 0);
                const bool take  = (lower == up) ? (ok < key) : (ok > key);
                if (take) { key = ok; sv = os; }
            }
        }

        const int npair = (n + 1) >> 1;
        int it = 0;
        for (; it + 3 < npair; it += 4) {
            PAIR(it) PAIR(it + 1) PAIR(it + 2) PAIR(it + 3)
        }
        for (; it < npair; ++it) { PAIR(it) }
    }

    // combine halves: commutative add -> identical in both lanes, deterministic
    acc.x += __shfl_xor(acc.x, 32);
    acc.y += __shfl_xor(acc.y, 32);
    acc.z += __shfl_xor(acc.z, 32);
    acc.w += __shfl_xor(acc.w, 32);

    if (half == 0) {
        usv4 o;
        o.x = f2bf(acc.x); o.y = f2bf(acc.y);
        o.z = f2bf(acc.z); o.w = f2bf(acc.w);
        *reinterpret_cast<usv4*>(h0 + (i64)node * D + c4) = o;
    }
}

// ===========================================================================
// Fused MLP: out = relu(h0 @ W1 + b1) @ W2 + b2, h1 tile staged in LDS.
// 782 blocks x 256 thr; block owns 128 rows; wave owns 32 cols (all 8 subs).
// m92-verified 16x16x32 maps: A row=lane&15, k=8*(lane>>4)+j; B col=lane&15,
// same k-map; C col=lane&15, row=(lane>>4)*4+reg.
// h1 LDS stride 136 shorts (272B = 68 words): uniform bank spread on b128 reads.
// ===========================================================================
__global__ __launch_bounds__(256) void mlp_fused_kernel(
    const unsigned short* __restrict__ hin,   // [ROWS_PAD][D] bf16 (pads zeroed)
    const float* __restrict__ w1, const float* __restrict__ b1,
    const float* __restrict__ w2, const float* __restrict__ b2,
    float* __restrict__ out)                  // [N_NODES][D] f32
{
    __shared__ unsigned short h1[128][136];   // 34816 B

    const int tid  = threadIdx.x;
    const int wave = tid >> 6;
    const int lane = tid & 63;
    const int g    = lane >> 4;
    const int lr   = lane & 15;
    const int colbase = wave * 32;
    const int rowbase0 = blockIdx.x * 128;

    // ---- layer 1 ----
    bf16x8 bfrag[4][2];
    #pragma unroll
    for (int ks = 0; ks < 4; ++ks) {
        #pragma unroll
        for (int nt = 0; nt < 2; ++nt) {
            const int col = colbase + nt * 16 + lr;
            const int k0  = ks * 32 + g * 8;
            bf16x8 f;
            #pragma unroll
            for (int j = 0; j < 8; ++j)
                f[j] = (short)f2bf(w1[(k0 + j) * D + col]);
            bfrag[ks][nt] = f;
        }
    }
    float bc0 = b1[colbase + lr];
    float bc1 = b1[colbase + 16 + lr];

    #pragma unroll 1
    for (int sub = 0; sub < 8; ++sub) {
        const int arow = rowbase0 + sub * 16 + lr;

        bf16x8 afrag[4];
        #pragma unroll
        for (int ks = 0; ks < 4; ++ks)
            afrag[ks] = *reinterpret_cast<const bf16x8*>(
                hin + (i64)arow * D + ks * 32 + g * 8);

        f32x4 acc0 = { bc0, bc0, bc0, bc0 };
        f32x4 acc1 = { bc1, bc1, bc1, bc1 };
        #pragma unroll
        for (int ks = 0; ks < 4; ++ks) {
            acc0 = __builtin_amdgcn_mfma_f32_16x16x32_bf16(afrag[ks], bfrag[ks][0], acc0, 0, 0, 0);
            acc1 = __builtin_amdgcn_mfma_f32_16x16x32_bf16(afrag[ks], bfrag[ks][1], acc1, 0, 0, 0);
        }

        #pragma unroll
        for (int r = 0; r < 4; ++r) {
            const int rl = sub * 16 + g * 4 + r;
            h1[rl][colbase + lr]      = f2bf(fmaxf(acc0[r], 0.f));
            h1[rl][colbase + 16 + lr] = f2bf(fmaxf(acc1[r], 0.f));
        }
    }

    __syncthreads();

    // ---- layer 2 (reuse bfrag regs) ----
    #pragma unroll
    for (int ks = 0; ks < 4; ++ks) {
        #pragma unroll
        for (int nt = 0; nt < 2; ++nt) {
            const int col = colbase + nt * 16 + lr;
            const int k0  = ks * 32 + g * 8;
            bf16x8 f;
            #pragma unroll
            for (int j = 0; j < 8; ++j)
                f[j] = (short)f2bf(w2[(k0 + j) * D + col]);
            bfrag[ks][nt] = f;
        }
    }
    bc0 = b2[colbase + lr];
    bc1 = b2[colbase + 16 + lr];

    #pragma unroll 1
    for (int sub = 0; sub < 8; ++sub) {
        const int rl = sub * 16 + lr;

        bf16x8 afrag[4];
        #pragma unroll
        for (int ks = 0; ks < 4; ++ks)
            afrag[ks] = *reinterpret_cast<const bf16x8*>(&h1[rl][ks * 32 + g * 8]);

        f32x4 acc0 = { bc0, bc0, bc0, bc0 };
        f32x4 acc1 = { bc1, bc1, bc1, bc1 };
        #pragma unroll
        for (int ks = 0; ks < 4; ++ks) {
            acc0 = __builtin_amdgcn_mfma_f32_16x16x32_bf16(afrag[ks], bfrag[ks][0], acc0, 0, 0, 0);
            acc1 = __builtin_amdgcn_mfma_f32_16x16x32_bf16(afrag[ks], bfrag[ks][1], acc1, 0, 0, 0);
        }

        #pragma unroll
        for (int r = 0; r < 4; ++r) {
            const int orow = rowbase0 + sub * 16 + g * 4 + r;
            if (orow < N_NODES) {
                out[(i64)orow * D + colbase + lr]      = acc0[r];
                out[(i64)orow * D + colbase + 16 + lr] = acc1[r];
            }
        }
    }
}

// ===========================================================================
// Fallback path (R2-proven) — only if ws too small
// ===========================================================================
__global__ __launch_bounds__(256) void init_acc_kernel(
    const float* __restrict__ x, float* __restrict__ acc)
{
    const int i = blockIdx.x * blockDim.x + threadIdx.x;
    const int n = N_NODES * D / 4;
    if (i < n)
        reinterpret_cast<float4*>(acc)[i] = reinterpret_cast<const float4*>(x)[i];
}

__global__ __launch_bounds__(256) void edge_scatter_kernel(
    const float* __restrict__ x,
    const int*  __restrict__ src,
    const int*  __restrict__ dst,
    const float* __restrict__ ea,
    float* __restrict__ acc)
{
    const int lane = threadIdx.x & 31;
    const int grp  = threadIdx.x >> 5;
    const i64 e = (i64)blockIdx.x * 8 + grp;
    if (e >= N_EDGES) return;
    const int s = src[e];
    const int d = dst[e];
    const int j = lane * 4;
    const float4 xv = *reinterpret_cast<const float4*>(x  + (i64)s * D + j);
    const float4 ev = *reinterpret_cast<const float4*>(ea + e * D + j);
    float4 m;
    m.x = fmaxf(xv.x + ev.x, 0.0f);
    m.y = fmaxf(xv.y + ev.y, 0.0f);
    m.z = fmaxf(xv.z + ev.z, 0.0f);
    m.w = fmaxf(xv.w + ev.w, 0.0f);
    float* pp = acc + (i64)d * D + j;
    atomicAdd(pp + 0, m.x);
    atomicAdd(pp + 1, m.y);
    atomicAdd(pp + 2, m.z);
    atomicAdd(pp + 3, m.w);
}

#define MLP_THREADS 512
#define ROWS_PER_CHUNK 16
#define CHUNKS_PER_BLOCK 4
#define ROWS_PER_BLOCK (ROWS_PER_CHUNK * CHUNKS_PER_BLOCK)

template<bool RELU>
__global__ __launch_bounds__(MLP_THREADS) void mlp_layer_kernel(
    const float* __restrict__ hin,
    const float* __restrict__ w,
    const float* __restrict__ b,
    float* __restrict__ hout)
{
    __shared__ float ws_[D * D];
    __shared__ float bs_[D];
    __shared__ float hrow[ROWS_PER_CHUNK][D];

    const int tid = threadIdx.x;
    for (int t = tid; t < D * D / 4; t += MLP_THREADS)
        reinterpret_cast<float4*>(ws_)[t] = reinterpret_cast<const float4*>(w)[t];
    if (tid < D) bs_[tid] = b[tid];

    const int j = tid & (D - 1);
    const int q = tid >> 7;
    const int rowBase = blockIdx.x * ROWS_PER_BLOCK;

    for (int c = 0; c < CHUNKS_PER_BLOCK; ++c) {
        const int chunkRow = rowBase + c * ROWS_PER_CHUNK;
        __syncthreads();
        {
            const int r   = tid >> 5;
            const int col = (tid & 31) * 4;
            const int gi  = chunkRow + r;
            float4 v = make_float4(0.f, 0.f, 0.f, 0.f);
            if (gi < N_NODES)
                v = *reinterpret_cast<const float4*>(hin + (i64)gi * D + col);
            *reinterpret_cast<float4*>(&hrow[r][col]) = v;
        }
        __syncthreads();

        float acc0 = bs_[j], acc1 = bs_[j], acc2 = bs_[j], acc3 = bs_[j];
        const int r0 = q * 4;
        #pragma unroll 4
        for (int k = 0; k < D; ++k) {
            const float wv = ws_[k * D + j];
            acc0 = fmaf(hrow[r0 + 0][k], wv, acc0);
            acc1 = fmaf(hrow[r0 + 1][k], wv, acc1);
            acc2 = fmaf(hrow[r0 + 2][k], wv, acc2);
            acc3 = fmaf(hrow[r0 + 3][k], wv, acc3);
        }
        if (RELU) {
            acc0 = fmaxf(acc0, 0.f); acc1 = fmaxf(acc1, 0.f);
            acc2 = fmaxf(acc2, 0.f); acc3 = fmaxf(acc3, 0.f);
        }
        const int gi = chunkRow + r0;
        if (gi + 0 < N_NODES) hout[(i64)(gi + 0) * D + j] = acc0;
        if (gi + 1 < N_NODES) hout[(i64)(gi + 1) * D + j] = acc1;
        if (gi + 2 < N_NODES) hout[(i64)(gi + 2) * D + j] = acc2;
        if (gi + 3 < N_NODES) hout[(i64)(gi + 3) * D + j] = acc3;
    }
}

// ===========================================================================
extern "C" void kernel_launch(void* const* d_in, const int* in_sizes, int n_in,
                              void* d_out, int out_size, void* d_ws, size_t ws_size,
                              hipStream_t stream)
{
    const float* x  = (const float*)d_in[0];
    const int*   ei = (const int*)  d_in[1];   // [2, E] int32
    const float* ea = (const float*)d_in[2];
    const float* w1 = (const float*)d_in[3];
    const float* b1 = (const float*)d_in[4];
    const float* w2 = (const float*)d_in[5];
    const float* b2 = (const float*)d_in[6];
    float* out = (float*)d_out;

    const int* src = ei;
    const int* dst = ei + N_EDGES;

    // ws layout: counts|offsets|cursor|blockSums | bucket2 int2[E] | xb bf16 | h0 bf16
    const size_t INT_REGION = (size_t)N_NODES + (N_NODES + 1) + N_NODES + 128;
    const size_t X_ELEMS    = (size_t)N_NODES * D;
    const size_t H_ELEMS    = (size_t)ROWS_PAD * D;
    const size_t WS_NEEDED  = INT_REGION * 4 + 64 + (size_t)N_EDGES * 8 + 64
                            + (X_ELEMS + H_ELEMS) * 2;

    if (ws_size >= WS_NEEDED) {
        int* counts    = (int*)d_ws;
        int* offsets   = counts + N_NODES;
        int* cursor    = offsets + (N_NODES + 1);
        int* blockSums = cursor + N_NODES;
        uintptr_t p = (uintptr_t)(blockSums + 128);
        p = (p + 63) & ~(uintptr_t)63;
        int2* bucket2 = (int2*)p;
        p = (uintptr_t)(bucket2 + N_EDGES);
        p = (p + 63) & ~(uintptr_t)63;
        unsigned short* xb = (unsigned short*)p;
        unsigned short* h0 = xb + X_ELEMS;

        prep_kernel<<<(int)(X_ELEMS / 8 + 255) / 256, 256, 0, stream>>>(x, xb, counts, h0);
        hist_kernel<<<(N_EDGES + 255) / 256, 256, 0, stream>>>(dst, counts);
        scan_pass1<<<N_CHUNKS, SCAN_THREADS, 0, stream>>>(counts, blockSums);
        scan_pass2<<<1, 128, 0, stream>>>(blockSums, offsets);
        scan_pass3<<<N_CHUNKS, SCAN_THREADS, 0, stream>>>(counts, blockSums, offsets, cursor);
        fill2_kernel<<<(N_EDGES + 255) / 256, 256, 0, stream>>>(src, dst, cursor, bucket2);
        gather_kernel<<<(N_NODES + 3) / 4, 256, 0, stream>>>(xb, ea, offsets, bucket2, h0);
        mlp_fused_kernel<<<ROWS_PAD / 128, 256, 0, stream>>>(h0, w1, b1, w2, b2, out);
    } else {
        const int n = N_NODES * D / 4;
        init_acc_kernel<<<(n + 255) / 256, 256, 0, stream>>>(x, out);
        edge_scatter_kernel<<<(N_EDGES + 7) / 8, 256, 0, stream>>>(x, src, dst, ea, out);
        const int blocks = (N_NODES + ROWS_PER_BLOCK - 1) / ROWS_PER_BLOCK;
        mlp_layer_kernel<true ><<<blocks, MLP_THREADS, 0, stream>>>(out, w1, b1, out);
        mlp_layer_kernel<false><<<blocks, MLP_THREADS, 0, stream>>>(out, w2, b2, out);
    }
}